// Round 10
// baseline (135.519 us; speedup 1.0000x reference)
//
#include <hip/hip_runtime.h>
#include <math.h>

typedef __attribute__((ext_vector_type(8))) _Float16 f16x8;
typedef __attribute__((ext_vector_type(4))) float f32x4;

#define NPIX 4096
#define C_DIM 128
#define SCALE 0.08838834764831845f   // 1/sqrt(128), folded into X conversion

// ws: fp16 Y panel [b][k][c] (4 MB, granule-XOR swizzled rows of 256B), then partials
#define WS_PART ((size_t)4 << 20)
#define WS_NEED (((size_t)4 << 20) + (size_t)16384 * 6 * 4)

// ---------------- conv: y fp32 [c][k] -> fp16 panel [k][c], XCD-matched (r7-r9, validated) ----------------
__global__ __launch_bounds__(256) void conv_y(const float* __restrict__ y,
                                              char* __restrict__ ws)
{
    __shared__ float T[32][132];
    const int wg  = blockIdx.x;
    const int xcd = wg & 7;
    const int b   = xcd >> 1;
    const int sl  = ((xcd & 1) << 6) | (wg >> 3);
    const int k0  = sl * 32;
    const int t   = threadIdx.x;

    {   // read 128c x 32k, coalesced
        const int c = t >> 1, half = t & 1;
        const float* srow = y + ((size_t)b * C_DIM + c) * NPIX + k0 + half * 16;
        float4 rv[4];
        #pragma unroll
        for (int u = 0; u < 4; ++u) rv[u] = *(const float4*)(srow + u * 4);
        #pragma unroll
        for (int u = 0; u < 4; ++u) {
            T[half * 16 + u * 4 + 0][c] = rv[u].x;
            T[half * 16 + u * 4 + 1][c] = rv[u].y;
            T[half * 16 + u * 4 + 2][c] = rv[u].z;
            T[half * 16 + u * 4 + 3][c] = rv[u].w;
        }
    }
    __syncthreads();

    char* panel = ws + (size_t)b * (NPIX * 256);
    const int k = t >> 3, g2 = t & 7;
    f16x8 v0, v1;
    #pragma unroll
    for (int m = 0; m < 8; ++m) {
        v0[m] = (_Float16)T[k][g2 * 16 + m];
        v1[m] = (_Float16)T[k][g2 * 16 + 8 + m];
    }
    const int key = k0 + k, s = key & 7;           // granule-XOR swizzle per key row
    char* drow = panel + (size_t)key * 256;
    *(f16x8*)(drow + (((2 * g2)     ^ s) << 4)) = v0;
    *(f16x8*)(drow + (((2 * g2 + 1) ^ s) << 4)) = v1;
}

// ---------------- main: K-split, 4 waves/SIMD, wave-private pipeline, single-pass fp16 ----------------
// Grid 512 = (b, qtile, key-half): 2 blocks/CU (128 KB LDS/CU), 16 waves/CU. Each block
// streams HALF the panel (0.5 MB) -> per-CU traffic unchanged vs r9, latency hiding x2.
// Wave w stages/reads only rows [w*16,w*16+16) of each 128-key tile; per-wave vmcnt(0) sync.
__global__ __launch_bounds__(512, 4) void uv_main(const char* __restrict__ ws,
                                                  const float* __restrict__ x,
                                                  float* __restrict__ out)
{
    __shared__ __align__(16) char Ys[2][32768];    // dbuf: 128 keys x 256B fp16

    const int t = threadIdx.x, w = t >> 6, l = t & 63;
    const int n16 = l & 15, quad = l >> 4;
    const int wg  = blockIdx.x;
    const int xcd = wg & 7;
    const int b   = xcd >> 1;                      // 2 XCDs per batch
    const int ks  = xcd & 1;                       // key half: [ks*2048, ks*2048+2048)
    const int qt  = wg >> 3;                       // 0..63
    const int q0  = qt * 64;

    // ---- one-time: X B-fragments fp16 single-pass (scale folded). 64 VGPRs. ----
    f16x8 bx[4][4];                                // [cc][qg]
    {
        const float* xq = x + (size_t)b * C_DIM * NPIX + q0 + n16;
        #pragma unroll
        for (int cc = 0; cc < 4; ++cc)
            #pragma unroll
            for (int qg = 0; qg < 4; ++qg) {
                f16x8 hh;
                #pragma unroll
                for (int j = 0; j < 8; ++j)
                    hh[j] = (_Float16)(xq[(size_t)(cc * 32 + quad * 8 + j) * NPIX + qg * 16] * SCALE);
                bx[cc][qg] = hh;
            }
    }

    const char* gsrc = ws + (size_t)b * (NPIX * 256) + (size_t)ks * (2048 * 256);

    // A-frag read offsets (wave-private rows): A[m = n16][k = quad*8 + j], row = w*16 + n16
    const int arow = w * 16 + n16;
    int aoff[4];
    #pragma unroll
    for (int cc = 0; cc < 4; ++cc)
        aoff[cc] = arow * 256 + (((cc * 4 + quad) ^ (n16 & 7)) << 4);

    // staging: wave w copies its own rows [w*16, w*16+16): 4 x (64 lanes x 16B)
    int soff[4];
    #pragma unroll
    for (int i = 0; i < 4; ++i) soff[i] = (w * 16 + i * 4) * 256 + l * 16;

    // preload tile 0 into buf 0
    #pragma unroll
    for (int i = 0; i < 4; ++i)
        __builtin_amdgcn_global_load_lds(
            (const __attribute__((address_space(1))) void*)(gsrc + soff[i]),
            (__attribute__((address_space(3))) void*)(&Ys[0][soff[i]]), 16, 0, 0);

    // D rows: tile-local key = w*16 + quad*4 + r; gx = (key&63)+0.5
    const float gxb = (float)((w & 3) * 16 + quad * 4) + 0.5f;
    const float gyw = (float)(ks * 32 + (w >> 2)) + 0.5f;      // + 2*kt per tile
    float den[4] = {0.f, 0.f, 0.f, 0.f}, nu[4] = {0.f, 0.f, 0.f, 0.f}, nv[4] = {0.f, 0.f, 0.f, 0.f};

    for (int kt = 0; kt < 16; ++kt) {
        char* cur = Ys[kt & 1];

        // per-wave drain: only outstanding VM ops are THIS tile's 4 loads (issued one tile ago)
        __builtin_amdgcn_s_waitcnt(0x0F70 /* vmcnt(0), lgkm/exp unconstrained */);

        if (kt < 15) {   // issue NEXT tile into the other buffer
            const char* gt = gsrc + (size_t)(kt + 1) * 32768;
            char* nb = Ys[(kt & 1) ^ 1];
            #pragma unroll
            for (int i = 0; i < 4; ++i)
                __builtin_amdgcn_global_load_lds(
                    (const __attribute__((address_space(1))) void*)(gt + soff[i]),
                    (__attribute__((address_space(3))) void*)(&nb[soff[i]]), 16, 0, 0);
        }

        f32x4 acc[4];
        #pragma unroll
        for (int qg = 0; qg < 4; ++qg) acc[qg] = (f32x4){0.f, 0.f, 0.f, 0.f};

        #pragma unroll
        for (int cc = 0; cc < 4; ++cc) {
            const f16x8 A = *(const f16x8*)(cur + aoff[cc]);
            #pragma unroll
            for (int qg = 0; qg < 4; ++qg)
                acc[qg] = __builtin_amdgcn_mfma_f32_16x16x32_f16(A, bx[cc][qg], acc[qg], 0, 0, 0);
        }

        // softmax accumulation, no max subtraction (|s| <= ~7 -> exp safe in fp32)
        const float gy = 2.0f * (float)kt + gyw;
        #pragma unroll
        for (int qg = 0; qg < 4; ++qg) {
            float ps = 0.f, pc = 0.f;
            #pragma unroll
            for (int r = 0; r < 4; ++r) {
                const float p = __expf(acc[qg][r]);
                ps += p;
                pc += p * (float)r;                // inline-const multiplier
            }
            den[qg] += ps;
            nu[qg]  += pc + gxb * ps;
            nv[qg]  += gy * ps;
        }
    }

    // ---- reduce across quads (keys within wave), then across 8 waves via LDS ----
    #pragma unroll
    for (int qg = 0; qg < 4; ++qg) {
        #pragma unroll
        for (int mk = 16; mk <= 32; mk <<= 1) {
            den[qg] += __shfl_xor(den[qg], mk);
            nu[qg]  += __shfl_xor(nu[qg],  mk);
            nv[qg]  += __shfl_xor(nv[qg],  mk);
        }
    }
    __syncthreads();                  // waves re-converge; Ys reused as scratch
    float* red = (float*)&Ys[0][0];   // [8 waves][64 queries][3]
    if (quad == 0) {
        #pragma unroll
        for (int qg = 0; qg < 4; ++qg) {
            const int base = (w * 64 + qg * 16 + n16) * 3;
            red[base + 0] = den[qg];
            red[base + 1] = nu[qg];
            red[base + 2] = nv[qg];
        }
    }
    __syncthreads();
    if (t < 64) {
        float d = 0.f, u = 0.f, v = 0.f;
        #pragma unroll
        for (int ww = 0; ww < 8; ++ww) {
            d += red[(ww * 64 + t) * 3 + 0];
            u += red[(ww * 64 + t) * 3 + 1];
            v += red[(ww * 64 + t) * 3 + 2];
        }
        // partial for this key-half; merged by merge_k
        float* pp = (float*)(ws + WS_PART) + ((size_t)(b * NPIX + q0 + t) * 2 + ks) * 3;
        pp[0] = d; pp[1] = u; pp[2] = v;
    }
}

// ---------------- merge: combine 2 key-half partials, finalize ----------------
__global__ __launch_bounds__(256) void merge_k(const char* __restrict__ ws,
                                               float* __restrict__ out)
{
    const int id = blockIdx.x * 256 + threadIdx.x;      // 0..16383 = b*4096 + q
    const float* p = (const float*)(ws + WS_PART) + (size_t)id * 6;
    const float d = p[0] + p[3];
    const float u = p[1] + p[4];
    const float v = p[2] + p[5];
    const float inv = 1.0f / d;
    *(float2*)(out + (size_t)id * 2) =
        make_float2(u * inv * 0.03125f - 1.0f, v * inv * 0.03125f - 1.0f);
}

// ---------------- fallback (fp32 vector kernel, known-correct) if ws too small ----------------
__global__ __launch_bounds__(256, 2) void uv_attn_kernel(
    const float* __restrict__ x, const float* __restrict__ y, float* __restrict__ out)
{
    __shared__ float Xs[C_DIM][32];
    __shared__ float Ysf[64][128];
    const int tid = threadIdx.x;
    const int wgid = blockIdx.x;
    const int xcd = wgid & 7;
    const int b = xcd & 3;
    const int q0 = (((xcd >> 2) << 6) | (wgid >> 3)) * 32;
    const float* xb = x + (size_t)b * C_DIM * NPIX + q0;
    {
        const int cr = tid >> 3;
        const int cc = (tid & 7) << 2;
        #pragma unroll
        for (int i = 0; i < 4; ++i) {
            float4 v = *(const float4*)(xb + (size_t)(cr + (i << 5)) * NPIX + cc);
            v.x *= SCALE; v.y *= SCALE; v.z *= SCALE; v.w *= SCALE;
            *(float4*)(&Xs[cr + (i << 5)][cc]) = v;
        }
    }
    const int rg = tid >> 4;
    const int lane16 = tid & 15;
    const int r0 = rg << 1;
    const int col0 = lane16 << 3;
    float gxv[8];
    #pragma unroll
    for (int j2 = 0; j2 < 8; ++j2) gxv[j2] = (float)((col0 & 63) + j2) + 0.5f;
    const float gyb = (float)(lane16 >> 3) + 0.5f;
    float m_run[2] = {-INFINITY, -INFINITY};
    float den[2] = {0.f, 0.f}, nu[2] = {0.f, 0.f}, nv[2] = {0.f, 0.f};
    const int yr = tid >> 5;
    const int yc = (tid & 31) << 2;
    const float* ybase = y + (size_t)b * C_DIM * NPIX;
    for (int kt = 0; kt < 32; ++kt) {
        float S[2][8];
        #pragma unroll
        for (int r = 0; r < 2; ++r)
            #pragma unroll
            for (int j2 = 0; j2 < 8; ++j2) S[r][j2] = 0.f;
        #pragma unroll
        for (int cb = 0; cb < 2; ++cb) {
            __syncthreads();
            const float* yt = ybase + (size_t)(cb << 6) * NPIX + kt * 128;
            #pragma unroll
            for (int i = 0; i < 8; ++i)
                *(float4*)(&Ysf[yr + (i << 3)][yc]) =
                    *(const float4*)(yt + (size_t)(yr + (i << 3)) * NPIX + yc);
            __syncthreads();
            const int cbase = cb << 6;
            #pragma unroll 16
            for (int c = 0; c < 64; ++c) {
                const float2 xa = *(const float2*)(&Xs[cbase + c][r0]);
                const float4 ya = *(const float4*)(&Ysf[c][col0]);
                const float4 yb4 = *(const float4*)(&Ysf[c][col0 + 4]);
                S[0][0] += xa.x * ya.x;  S[0][1] += xa.x * ya.y;
                S[0][2] += xa.x * ya.z;  S[0][3] += xa.x * ya.w;
                S[0][4] += xa.x * yb4.x; S[0][5] += xa.x * yb4.y;
                S[0][6] += xa.x * yb4.z; S[0][7] += xa.x * yb4.w;
                S[1][0] += xa.y * ya.x;  S[1][1] += xa.y * ya.y;
                S[1][2] += xa.y * ya.z;  S[1][3] += xa.y * ya.w;
                S[1][4] += xa.y * yb4.x; S[1][5] += xa.y * yb4.y;
                S[1][6] += xa.y * yb4.z; S[1][7] += xa.y * yb4.w;
            }
        }
        const float gy = gyb + 2.0f * (float)kt;
        #pragma unroll
        for (int r = 0; r < 2; ++r) {
            float tmax = S[r][0];
            #pragma unroll
            for (int j2 = 1; j2 < 8; ++j2) tmax = fmaxf(tmax, S[r][j2]);
            #pragma unroll
            for (int mk = 8; mk >= 1; mk >>= 1) tmax = fmaxf(tmax, __shfl_xor(tmax, mk, 16));
            const float mnew = fmaxf(m_run[r], tmax);
            const float alpha = __expf(m_run[r] - mnew);
            m_run[r] = mnew;
            float psum = 0.f, pu = 0.f;
            #pragma unroll
            for (int j2 = 0; j2 < 8; ++j2) {
                const float p = __expf(S[r][j2] - mnew);
                psum += p; pu += p * gxv[j2];
            }
            den[r] = den[r] * alpha + psum;
            nu[r] = nu[r] * alpha + pu;
            nv[r] = nv[r] * alpha + gy * psum;
        }
    }
    #pragma unroll
    for (int r = 0; r < 2; ++r)
        #pragma unroll
        for (int mk = 8; mk >= 1; mk >>= 1) {
            den[r] += __shfl_xor(den[r], mk, 16);
            nu[r] += __shfl_xor(nu[r], mk, 16);
            nv[r] += __shfl_xor(nv[r], mk, 16);
        }
    if (lane16 == 0) {
        #pragma unroll
        for (int r = 0; r < 2; ++r) {
            const float inv = 1.0f / den[r];
            const int q = q0 + r0 + r;
            *(float2*)(out + ((size_t)b * NPIX + q) * 2) =
                make_float2(nu[r] * inv * 0.03125f - 1.0f, nv[r] * inv * 0.03125f - 1.0f);
        }
    }
}

extern "C" void kernel_launch(void* const* d_in, const int* in_sizes, int n_in,
                              void* d_out, int out_size, void* d_ws, size_t ws_size,
                              hipStream_t stream) {
    const float* x = (const float*)d_in[0];
    const float* y = (const float*)d_in[1];
    float* out = (float*)d_out;
    if (ws_size >= WS_NEED) {
        hipLaunchKernelGGL(conv_y, dim3(512), dim3(256), 0, stream, y, (char*)d_ws);
        hipLaunchKernelGGL(uv_main, dim3(512), dim3(512), 0, stream,
                           (const char*)d_ws, x, out);
        hipLaunchKernelGGL(merge_k, dim3(64), dim3(256), 0, stream,
                           (const char*)d_ws, out);
    } else {
        hipLaunchKernelGGL(uv_attn_kernel, dim3(512), dim3(256), 0, stream, x, y, out);
    }
}

// Round 11
// 95.522 us; speedup vs baseline: 1.4187x; 1.4187x over previous
//
#include <hip/hip_runtime.h>
#include <math.h>

typedef __attribute__((ext_vector_type(8))) _Float16 f16x8;
typedef __attribute__((ext_vector_type(4))) float f32x4;

#define NPIX 4096
#define C_DIM 128
#define SCALE 0.08838834764831845f   // 1/sqrt(128), folded into X conversion

// ws: fp16 Y panel [b][k][c] (4 MB, granule-XOR swizzled rows of 256B), then partials
#define WS_PART ((size_t)4 << 20)
#define WS_NEED (((size_t)4 << 20) + (size_t)16384 * 6 * 4)

// ---------------- conv: y fp32 [c][k] -> fp16 panel [k][c], XCD-matched (r7-r9, validated) ----------------
__global__ __launch_bounds__(256) void conv_y(const float* __restrict__ y,
                                              char* __restrict__ ws)
{
    __shared__ float T[32][132];
    const int wg  = blockIdx.x;
    const int xcd = wg & 7;
    const int b   = xcd >> 1;
    const int sl  = ((xcd & 1) << 6) | (wg >> 3);
    const int k0  = sl * 32;
    const int t   = threadIdx.x;

    {   // read 128c x 32k, coalesced
        const int c = t >> 1, half = t & 1;
        const float* srow = y + ((size_t)b * C_DIM + c) * NPIX + k0 + half * 16;
        float4 rv[4];
        #pragma unroll
        for (int u = 0; u < 4; ++u) rv[u] = *(const float4*)(srow + u * 4);
        #pragma unroll
        for (int u = 0; u < 4; ++u) {
            T[half * 16 + u * 4 + 0][c] = rv[u].x;
            T[half * 16 + u * 4 + 1][c] = rv[u].y;
            T[half * 16 + u * 4 + 2][c] = rv[u].z;
            T[half * 16 + u * 4 + 3][c] = rv[u].w;
        }
    }
    __syncthreads();

    char* panel = ws + (size_t)b * (NPIX * 256);
    const int k = t >> 3, g2 = t & 7;
    f16x8 v0, v1;
    #pragma unroll
    for (int m = 0; m < 8; ++m) {
        v0[m] = (_Float16)T[k][g2 * 16 + m];
        v1[m] = (_Float16)T[k][g2 * 16 + 8 + m];
    }
    const int key = k0 + k, s = key & 7;           // granule-XOR swizzle per key row
    char* drow = panel + (size_t)key * 256;
    *(f16x8*)(drow + (((2 * g2)     ^ s) << 4)) = v0;
    *(f16x8*)(drow + (((2 * g2 + 1) ^ s) << 4)) = v1;
}

// ---------------- main: K-split, wave-private pipeline, single-pass fp16 ----------------
// Grid 512 = (b, qtile, key-half): 2 blocks/CU (128 KB LDS/CU). Each block streams HALF
// the panel (0.5 MB) -> per-CU traffic same as r9, latency hiding x2.
// NOTE: no min-waves arg in __launch_bounds__ — r10's (512,4) made the compiler cap VGPRs
// at 64 (< the 64-reg bx array alone) and spill ~330 MB/dispatch to scratch. Natural usage
// ~115 VGPRs lands in the <=128 bin -> 4 waves/SIMD without any cap.
__global__ __launch_bounds__(512) void uv_main(const char* __restrict__ ws,
                                               const float* __restrict__ x,
                                               float* __restrict__ out)
{
    __shared__ __align__(16) char Ys[2][32768];    // dbuf: 128 keys x 256B fp16

    const int t = threadIdx.x, w = t >> 6, l = t & 63;
    const int n16 = l & 15, quad = l >> 4;
    const int wg  = blockIdx.x;
    const int xcd = wg & 7;
    const int b   = xcd >> 1;                      // 2 XCDs per batch
    const int ks  = xcd & 1;                       // key half: [ks*2048, ks*2048+2048)
    const int qt  = wg >> 3;                       // 0..63
    const int q0  = qt * 64;

    // ---- one-time: X B-fragments fp16 single-pass (scale folded). 64 VGPRs. ----
    f16x8 bx[4][4];                                // [cc][qg]
    {
        const float* xq = x + (size_t)b * C_DIM * NPIX + q0 + n16;
        #pragma unroll
        for (int cc = 0; cc < 4; ++cc)
            #pragma unroll
            for (int qg = 0; qg < 4; ++qg) {
                f16x8 hh;
                #pragma unroll
                for (int j = 0; j < 8; ++j)
                    hh[j] = (_Float16)(xq[(size_t)(cc * 32 + quad * 8 + j) * NPIX + qg * 16] * SCALE);
                bx[cc][qg] = hh;
            }
    }

    const char* gsrc = ws + (size_t)b * (NPIX * 256) + (size_t)ks * (2048 * 256);

    // A-frag read offsets (wave-private rows): A[m = n16][k = quad*8 + j], row = w*16 + n16
    const int arow = w * 16 + n16;
    int aoff[4];
    #pragma unroll
    for (int cc = 0; cc < 4; ++cc)
        aoff[cc] = arow * 256 + (((cc * 4 + quad) ^ (n16 & 7)) << 4);

    // staging: wave w copies its own rows [w*16, w*16+16): 4 x (64 lanes x 16B)
    int soff[4];
    #pragma unroll
    for (int i = 0; i < 4; ++i) soff[i] = (w * 16 + i * 4) * 256 + l * 16;

    // preload tile 0 into buf 0
    #pragma unroll
    for (int i = 0; i < 4; ++i)
        __builtin_amdgcn_global_load_lds(
            (const __attribute__((address_space(1))) void*)(gsrc + soff[i]),
            (__attribute__((address_space(3))) void*)(&Ys[0][soff[i]]), 16, 0, 0);

    // D rows: tile-local key = w*16 + quad*4 + r; gx = (key&63)+0.5
    const float gxb = (float)((w & 3) * 16 + quad * 4) + 0.5f;
    const float gyw = (float)(ks * 32 + (w >> 2)) + 0.5f;      // + 2*kt per tile
    float den[4] = {0.f, 0.f, 0.f, 0.f}, nu[4] = {0.f, 0.f, 0.f, 0.f}, nv[4] = {0.f, 0.f, 0.f, 0.f};

    for (int kt = 0; kt < 16; ++kt) {
        char* cur = Ys[kt & 1];

        // per-wave drain: only outstanding VM ops are THIS tile's 4 loads (issued one tile ago)
        __builtin_amdgcn_s_waitcnt(0x0F70 /* vmcnt(0), lgkm/exp unconstrained */);

        if (kt < 15) {   // issue NEXT tile into the other buffer
            const char* gt = gsrc + (size_t)(kt + 1) * 32768;
            char* nb = Ys[(kt & 1) ^ 1];
            #pragma unroll
            for (int i = 0; i < 4; ++i)
                __builtin_amdgcn_global_load_lds(
                    (const __attribute__((address_space(1))) void*)(gt + soff[i]),
                    (__attribute__((address_space(3))) void*)(&nb[soff[i]]), 16, 0, 0);
        }

        f32x4 acc[4];
        #pragma unroll
        for (int qg = 0; qg < 4; ++qg) acc[qg] = (f32x4){0.f, 0.f, 0.f, 0.f};

        #pragma unroll
        for (int cc = 0; cc < 4; ++cc) {
            const f16x8 A = *(const f16x8*)(cur + aoff[cc]);
            #pragma unroll
            for (int qg = 0; qg < 4; ++qg)
                acc[qg] = __builtin_amdgcn_mfma_f32_16x16x32_f16(A, bx[cc][qg], acc[qg], 0, 0, 0);
        }

        // softmax accumulation, no max subtraction (|s| <= ~7 -> exp safe in fp32)
        const float gy = 2.0f * (float)kt + gyw;
        #pragma unroll
        for (int qg = 0; qg < 4; ++qg) {
            float ps = 0.f, pc = 0.f;
            #pragma unroll
            for (int r = 0; r < 4; ++r) {
                const float p = __expf(acc[qg][r]);
                ps += p;
                pc += p * (float)r;                // inline-const multiplier
            }
            den[qg] += ps;
            nu[qg]  += pc + gxb * ps;
            nv[qg]  += gy * ps;
        }
    }

    // ---- reduce across quads (keys within wave), then across 8 waves via LDS ----
    #pragma unroll
    for (int qg = 0; qg < 4; ++qg) {
        #pragma unroll
        for (int mk = 16; mk <= 32; mk <<= 1) {
            den[qg] += __shfl_xor(den[qg], mk);
            nu[qg]  += __shfl_xor(nu[qg],  mk);
            nv[qg]  += __shfl_xor(nv[qg],  mk);
        }
    }
    __syncthreads();                  // waves re-converge; Ys reused as scratch
    float* red = (float*)&Ys[0][0];   // [8 waves][64 queries][3]
    if (quad == 0) {
        #pragma unroll
        for (int qg = 0; qg < 4; ++qg) {
            const int base = (w * 64 + qg * 16 + n16) * 3;
            red[base + 0] = den[qg];
            red[base + 1] = nu[qg];
            red[base + 2] = nv[qg];
        }
    }
    __syncthreads();
    if (t < 64) {
        float d = 0.f, u = 0.f, v = 0.f;
        #pragma unroll
        for (int ww = 0; ww < 8; ++ww) {
            d += red[(ww * 64 + t) * 3 + 0];
            u += red[(ww * 64 + t) * 3 + 1];
            v += red[(ww * 64 + t) * 3 + 2];
        }
        // partial for this key-half; merged by merge_k
        float* pp = (float*)(ws + WS_PART) + ((size_t)(b * NPIX + q0 + t) * 2 + ks) * 3;
        pp[0] = d; pp[1] = u; pp[2] = v;
    }
}

// ---------------- merge: combine 2 key-half partials, finalize ----------------
__global__ __launch_bounds__(256) void merge_k(const char* __restrict__ ws,
                                               float* __restrict__ out)
{
    const int id = blockIdx.x * 256 + threadIdx.x;      // 0..16383 = b*4096 + q
    const float* p = (const float*)(ws + WS_PART) + (size_t)id * 6;
    const float d = p[0] + p[3];
    const float u = p[1] + p[4];
    const float v = p[2] + p[5];
    const float inv = 1.0f / d;
    *(float2*)(out + (size_t)id * 2) =
        make_float2(u * inv * 0.03125f - 1.0f, v * inv * 0.03125f - 1.0f);
}

// ---------------- fallback (fp32 vector kernel, known-correct) if ws too small ----------------
__global__ __launch_bounds__(256, 2) void uv_attn_kernel(
    const float* __restrict__ x, const float* __restrict__ y, float* __restrict__ out)
{
    __shared__ float Xs[C_DIM][32];
    __shared__ float Ysf[64][128];
    const int tid = threadIdx.x;
    const int wgid = blockIdx.x;
    const int xcd = wgid & 7;
    const int b = xcd & 3;
    const int q0 = (((xcd >> 2) << 6) | (wgid >> 3)) * 32;
    const float* xb = x + (size_t)b * C_DIM * NPIX + q0;
    {
        const int cr = tid >> 3;
        const int cc = (tid & 7) << 2;
        #pragma unroll
        for (int i = 0; i < 4; ++i) {
            float4 v = *(const float4*)(xb + (size_t)(cr + (i << 5)) * NPIX + cc);
            v.x *= SCALE; v.y *= SCALE; v.z *= SCALE; v.w *= SCALE;
            *(float4*)(&Xs[cr + (i << 5)][cc]) = v;
        }
    }
    const int rg = tid >> 4;
    const int lane16 = tid & 15;
    const int r0 = rg << 1;
    const int col0 = lane16 << 3;
    float gxv[8];
    #pragma unroll
    for (int j2 = 0; j2 < 8; ++j2) gxv[j2] = (float)((col0 & 63) + j2) + 0.5f;
    const float gyb = (float)(lane16 >> 3) + 0.5f;
    float m_run[2] = {-INFINITY, -INFINITY};
    float den[2] = {0.f, 0.f}, nu[2] = {0.f, 0.f}, nv[2] = {0.f, 0.f};
    const int yr = tid >> 5;
    const int yc = (tid & 31) << 2;
    const float* ybase = y + (size_t)b * C_DIM * NPIX;
    for (int kt = 0; kt < 32; ++kt) {
        float S[2][8];
        #pragma unroll
        for (int r = 0; r < 2; ++r)
            #pragma unroll
            for (int j2 = 0; j2 < 8; ++j2) S[r][j2] = 0.f;
        #pragma unroll
        for (int cb = 0; cb < 2; ++cb) {
            __syncthreads();
            const float* yt = ybase + (size_t)(cb << 6) * NPIX + kt * 128;
            #pragma unroll
            for (int i = 0; i < 8; ++i)
                *(float4*)(&Ysf[yr + (i << 3)][yc]) =
                    *(const float4*)(yt + (size_t)(yr + (i << 3)) * NPIX + yc);
            __syncthreads();
            const int cbase = cb << 6;
            #pragma unroll 16
            for (int c = 0; c < 64; ++c) {
                const float2 xa = *(const float2*)(&Xs[cbase + c][r0]);
                const float4 ya = *(const float4*)(&Ysf[c][col0]);
                const float4 yb4 = *(const float4*)(&Ysf[c][col0 + 4]);
                S[0][0] += xa.x * ya.x;  S[0][1] += xa.x * ya.y;
                S[0][2] += xa.x * ya.z;  S[0][3] += xa.x * ya.w;
                S[0][4] += xa.x * yb4.x; S[0][5] += xa.x * yb4.y;
                S[0][6] += xa.x * yb4.z; S[0][7] += xa.x * yb4.w;
                S[1][0] += xa.y * ya.x;  S[1][1] += xa.y * ya.y;
                S[1][2] += xa.y * ya.z;  S[1][3] += xa.y * ya.w;
                S[1][4] += xa.y * yb4.x; S[1][5] += xa.y * yb4.y;
                S[1][6] += xa.y * yb4.z; S[1][7] += xa.y * yb4.w;
            }
        }
        const float gy = gyb + 2.0f * (float)kt;
        #pragma unroll
        for (int r = 0; r < 2; ++r) {
            float tmax = S[r][0];
            #pragma unroll
            for (int j2 = 1; j2 < 8; ++j2) tmax = fmaxf(tmax, S[r][j2]);
            #pragma unroll
            for (int mk = 8; mk >= 1; mk >>= 1) tmax = fmaxf(tmax, __shfl_xor(tmax, mk, 16));
            const float mnew = fmaxf(m_run[r], tmax);
            const float alpha = __expf(m_run[r] - mnew);
            m_run[r] = mnew;
            float psum = 0.f, pu = 0.f;
            #pragma unroll
            for (int j2 = 0; j2 < 8; ++j2) {
                const float p = __expf(S[r][j2] - mnew);
                psum += p; pu += p * gxv[j2];
            }
            den[r] = den[r] * alpha + psum;
            nu[r] = nu[r] * alpha + pu;
            nv[r] = nv[r] * alpha + gy * psum;
        }
    }
    #pragma unroll
    for (int r = 0; r < 2; ++r)
        #pragma unroll
        for (int mk = 8; mk >= 1; mk >>= 1) {
            den[r] += __shfl_xor(den[r], mk, 16);
            nu[r] += __shfl_xor(nu[r], mk, 16);
            nv[r] += __shfl_xor(nv[r], mk, 16);
        }
    if (lane16 == 0) {
        #pragma unroll
        for (int r = 0; r < 2; ++r) {
            const float inv = 1.0f / den[r];
            const int q = q0 + r0 + r;
            *(float2*)(out + ((size_t)b * NPIX + q) * 2) =
                make_float2(nu[r] * inv * 0.03125f - 1.0f, nv[r] * inv * 0.03125f - 1.0f);
        }
    }
}

extern "C" void kernel_launch(void* const* d_in, const int* in_sizes, int n_in,
                              void* d_out, int out_size, void* d_ws, size_t ws_size,
                              hipStream_t stream) {
    const float* x = (const float*)d_in[0];
    const float* y = (const float*)d_in[1];
    float* out = (float*)d_out;
    if (ws_size >= WS_NEED) {
        hipLaunchKernelGGL(conv_y, dim3(512), dim3(256), 0, stream, y, (char*)d_ws);
        hipLaunchKernelGGL(uv_main, dim3(512), dim3(512), 0, stream,
                           (const char*)d_ws, x, out);
        hipLaunchKernelGGL(merge_k, dim3(64), dim3(256), 0, stream,
                           (const char*)d_ws, out);
    } else {
        hipLaunchKernelGGL(uv_attn_kernel, dim3(512), dim3(256), 0, stream, x, y, out);
    }
}

// Round 12
// 90.524 us; speedup vs baseline: 1.4970x; 1.0552x over previous
//
#include <hip/hip_runtime.h>
#include <math.h>

typedef __attribute__((ext_vector_type(8))) _Float16 f16x8;
typedef __attribute__((ext_vector_type(4))) float f32x4;

#define NPIX 4096
#define C_DIM 128
// 1/sqrt(128) * log2(e): scores arrive in log2-space -> exp2 (v_exp_f32 native, no mul)
#define SCALE2 0.12752064638518208f

#if __has_builtin(__builtin_amdgcn_exp2f)
#define EXP2(x) __builtin_amdgcn_exp2f(x)
#else
#define EXP2(x) exp2f(x)
#endif

// ws: fp16 Y panel [b][k][c], rows of 256B, granule-XOR swizzled. 4 MB.
#define WS_NEED ((size_t)4 << 20)

// ---------------- conv: y fp32 [c][k] -> fp16 panel [k][c], XCD-matched (r7-r11, validated) ----------------
__global__ __launch_bounds__(256) void conv_y(const float* __restrict__ y,
                                              char* __restrict__ ws)
{
    __shared__ float T[32][132];
    const int wg  = blockIdx.x;
    const int xcd = wg & 7;
    const int b   = xcd >> 1;
    const int sl  = ((xcd & 1) << 6) | (wg >> 3);
    const int k0  = sl * 32;
    const int t   = threadIdx.x;

    {   // read 128c x 32k, coalesced
        const int c = t >> 1, half = t & 1;
        const float* srow = y + ((size_t)b * C_DIM + c) * NPIX + k0 + half * 16;
        float4 rv[4];
        #pragma unroll
        for (int u = 0; u < 4; ++u) rv[u] = *(const float4*)(srow + u * 4);
        #pragma unroll
        for (int u = 0; u < 4; ++u) {
            T[half * 16 + u * 4 + 0][c] = rv[u].x;
            T[half * 16 + u * 4 + 1][c] = rv[u].y;
            T[half * 16 + u * 4 + 2][c] = rv[u].z;
            T[half * 16 + u * 4 + 3][c] = rv[u].w;
        }
    }
    __syncthreads();

    char* panel = ws + (size_t)b * (NPIX * 256);
    const int k = t >> 3, g2 = t & 7;
    f16x8 v0, v1;
    #pragma unroll
    for (int m = 0; m < 8; ++m) {
        v0[m] = (_Float16)T[k][g2 * 16 + m];
        v1[m] = (_Float16)T[k][g2 * 16 + 8 + m];
    }
    const int key = k0 + k, s = key & 7;           // granule-XOR swizzle per key row
    char* drow = panel + (size_t)key * 256;
    *(f16x8*)(drow + (((2 * g2)     ^ s) << 4)) = v0;
    *(f16x8*)(drow + (((2 * g2 + 1) ^ s) << 4)) = v1;
}

// ---------------- main: TQ=64, triple-buffered 2-deep wave-private pipeline, exp2 softmax ----------------
// Grid 256 = 1 block/CU (8 waves = 2/SIMD), 96 KB LDS. Wave w stages/reads only rows
// [w*16, w*16+16) of each 128-key tile. Issue tile kt+2, then s_waitcnt vmcnt(8): drains
// tile kt only, keeps kt+1 in flight -> every load gets ~2 tiles of latency cover
// (the "never vmcnt(0)" pattern; expressible because the pipeline is wave-private).
__global__ __launch_bounds__(512) void uv_main(const char* __restrict__ ws,
                                               const float* __restrict__ x,
                                               float* __restrict__ out)
{
    __shared__ __align__(16) char Ys[3][32768];    // triple buffer: 128 keys x 256B fp16

    const int t = threadIdx.x, w = t >> 6, l = t & 63;
    const int n16 = l & 15, quad = l >> 4;
    const int wg  = blockIdx.x;
    const int xcd = wg & 7;
    const int b   = xcd >> 1;                      // 2 XCDs per batch, 1MB panel L2-resident
    const int qt  = ((xcd & 1) << 5) | (wg >> 3);  // 0..63
    const int q0  = qt * 64;

    // ---- one-time: X B-fragments fp16 (SCALE2 folded: scores in log2-space). 64 VGPRs. ----
    f16x8 bx[4][4];                                // [cc][qg]
    {
        const float* xq = x + (size_t)b * C_DIM * NPIX + q0 + n16;
        #pragma unroll
        for (int cc = 0; cc < 4; ++cc)
            #pragma unroll
            for (int qg = 0; qg < 4; ++qg) {
                f16x8 hh;
                #pragma unroll
                for (int j = 0; j < 8; ++j)
                    hh[j] = (_Float16)(xq[(size_t)(cc * 32 + quad * 8 + j) * NPIX + qg * 16] * SCALE2);
                bx[cc][qg] = hh;
            }
    }

    const char* panel = ws + (size_t)b * (NPIX * 256);

    // A-frag read offsets (wave-private rows): A[m = n16][k = quad*8 + j], row = w*16 + n16
    const int arow = w * 16 + n16;
    int aoff[4];
    #pragma unroll
    for (int cc = 0; cc < 4; ++cc)
        aoff[cc] = arow * 256 + (((cc * 4 + quad) ^ (n16 & 7)) << 4);

    // staging: wave w copies its own rows [w*16, w*16+16): 4 x (64 lanes x 16B)
    int soff[4];
    #pragma unroll
    for (int i = 0; i < 4; ++i) soff[i] = (w * 16 + i * 4) * 256 + l * 16;

    // preload tiles 0,1 into bufs 0,1
    #pragma unroll
    for (int pb = 0; pb < 2; ++pb) {
        const char* gt = panel + (size_t)pb * 32768;
        #pragma unroll
        for (int i = 0; i < 4; ++i)
            __builtin_amdgcn_global_load_lds(
                (const __attribute__((address_space(1))) void*)(gt + soff[i]),
                (__attribute__((address_space(3))) void*)(&Ys[pb][soff[i]]), 16, 0, 0);
    }

    // D rows: tile-local key = w*16 + quad*4 + r; gx[r] = (key&63)+0.5 precomputed per lane
    float gxv[4];
    #pragma unroll
    for (int r = 0; r < 4; ++r) gxv[r] = (float)((w & 3) * 16 + quad * 4 + r) + 0.5f;
    const float gyw = (float)(w >> 2) + 0.5f;      // gy = 2*kt + gyw
    float den[4] = {0.f, 0.f, 0.f, 0.f}, nu[4] = {0.f, 0.f, 0.f, 0.f}, nv[4] = {0.f, 0.f, 0.f, 0.f};

    int bufc = 0;                                  // kt % 3
    for (int kt = 0; kt < 32; ++kt) {
        char* cur = Ys[bufc];

        if (kt < 30) {   // issue tile kt+2, then drain ONLY tile kt (vmcnt(8): kt+1 stays in flight)
            int bufn = bufc + 2; if (bufn >= 3) bufn -= 3;
            const char* gt = panel + (size_t)(kt + 2) * 32768;
            char* nb = Ys[bufn];
            #pragma unroll
            for (int i = 0; i < 4; ++i)
                __builtin_amdgcn_global_load_lds(
                    (const __attribute__((address_space(1))) void*)(gt + soff[i]),
                    (__attribute__((address_space(3))) void*)(&nb[soff[i]]), 16, 0, 0);
            __builtin_amdgcn_s_waitcnt(0x0F78);    // vmcnt(8): oldest 4 (tile kt) drained
        } else {
            __builtin_amdgcn_s_waitcnt(0x0F70);    // tail: vmcnt(0)
        }

        f32x4 acc[4];
        #pragma unroll
        for (int qg = 0; qg < 4; ++qg) acc[qg] = (f32x4){0.f, 0.f, 0.f, 0.f};

        #pragma unroll
        for (int cc = 0; cc < 4; ++cc) {
            const f16x8 A = *(const f16x8*)(cur + aoff[cc]);
            #pragma unroll
            for (int qg = 0; qg < 4; ++qg)
                acc[qg] = __builtin_amdgcn_mfma_f32_16x16x32_f16(A, bx[cc][qg], acc[qg], 0, 0, 0);
        }

        // softmax accumulation in log2-space: p = 2^s (v_exp_f32 native, no ln2 mul)
        const float gy = 2.0f * (float)kt + gyw;
        #pragma unroll
        for (int qg = 0; qg < 4; ++qg) {
            float ps = 0.f, pc = 0.f;
            #pragma unroll
            for (int r = 0; r < 4; ++r) {
                const float p = EXP2(acc[qg][r]);
                ps += p;
                pc += p * gxv[r];
            }
            den[qg] += ps;
            nu[qg]  += pc;
            nv[qg]  += gy * ps;
        }
        ++bufc; if (bufc >= 3) bufc -= 3;
    }

    // ---- reduce across quads (keys within wave), then across 8 waves via LDS ----
    #pragma unroll
    for (int qg = 0; qg < 4; ++qg) {
        #pragma unroll
        for (int mk = 16; mk <= 32; mk <<= 1) {
            den[qg] += __shfl_xor(den[qg], mk);
            nu[qg]  += __shfl_xor(nu[qg],  mk);
            nv[qg]  += __shfl_xor(nv[qg],  mk);
        }
    }
    __syncthreads();                  // waves re-converge; Ys reused as scratch
    float* red = (float*)&Ys[0][0];   // [8 waves][64 queries][3]
    if (quad == 0) {
        #pragma unroll
        for (int qg = 0; qg < 4; ++qg) {
            const int base = (w * 64 + qg * 16 + n16) * 3;
            red[base + 0] = den[qg];
            red[base + 1] = nu[qg];
            red[base + 2] = nv[qg];
        }
    }
    __syncthreads();
    if (t < 64) {
        float d = 0.f, u = 0.f, v = 0.f;
        #pragma unroll
        for (int ww = 0; ww < 8; ++ww) {
            d += red[(ww * 64 + t) * 3 + 0];
            u += red[(ww * 64 + t) * 3 + 1];
            v += red[(ww * 64 + t) * 3 + 2];
        }
        const float inv = 1.0f / d;
        *(float2*)(out + ((size_t)b * NPIX + q0 + t) * 2) =
            make_float2(u * inv * 0.03125f - 1.0f, v * inv * 0.03125f - 1.0f);
    }
}

// ---------------- fallback (fp32 vector kernel, known-correct) if ws too small ----------------
__global__ __launch_bounds__(256, 2) void uv_attn_kernel(
    const float* __restrict__ x, const float* __restrict__ y, float* __restrict__ out)
{
    __shared__ float Xs[C_DIM][32];
    __shared__ float Ysf[64][128];
    const float SCALE = 0.08838834764831845f;
    const int tid = threadIdx.x;
    const int wgid = blockIdx.x;
    const int xcd = wgid & 7;
    const int b = xcd & 3;
    const int q0 = (((xcd >> 2) << 6) | (wgid >> 3)) * 32;
    const float* xb = x + (size_t)b * C_DIM * NPIX + q0;
    {
        const int cr = tid >> 3;
        const int cc = (tid & 7) << 2;
        #pragma unroll
        for (int i = 0; i < 4; ++i) {
            float4 v = *(const float4*)(xb + (size_t)(cr + (i << 5)) * NPIX + cc);
            v.x *= SCALE; v.y *= SCALE; v.z *= SCALE; v.w *= SCALE;
            *(float4*)(&Xs[cr + (i << 5)][cc]) = v;
        }
    }
    const int rg = tid >> 4;
    const int lane16 = tid & 15;
    const int r0 = rg << 1;
    const int col0 = lane16 << 3;
    float gxv[8];
    #pragma unroll
    for (int j2 = 0; j2 < 8; ++j2) gxv[j2] = (float)((col0 & 63) + j2) + 0.5f;
    const float gyb = (float)(lane16 >> 3) + 0.5f;
    float m_run[2] = {-INFINITY, -INFINITY};
    float den[2] = {0.f, 0.f}, nu[2] = {0.f, 0.f}, nv[2] = {0.f, 0.f};
    const int yr = tid >> 5;
    const int yc = (tid & 31) << 2;
    const float* ybase = y + (size_t)b * C_DIM * NPIX;
    for (int kt = 0; kt < 32; ++kt) {
        float S[2][8];
        #pragma unroll
        for (int r = 0; r < 2; ++r)
            #pragma unroll
            for (int j2 = 0; j2 < 8; ++j2) S[r][j2] = 0.f;
        #pragma unroll
        for (int cb = 0; cb < 2; ++cb) {
            __syncthreads();
            const float* yt = ybase + (size_t)(cb << 6) * NPIX + kt * 128;
            #pragma unroll
            for (int i = 0; i < 8; ++i)
                *(float4*)(&Ysf[yr + (i << 3)][yc]) =
                    *(const float4*)(yt + (size_t)(yr + (i << 3)) * NPIX + yc);
            __syncthreads();
            const int cbase = cb << 6;
            #pragma unroll 16
            for (int c = 0; c < 64; ++c) {
                const float2 xa = *(const float2*)(&Xs[cbase + c][r0]);
                const float4 ya = *(const float4*)(&Ysf[c][col0]);
                const float4 yb4 = *(const float4*)(&Ysf[c][col0 + 4]);
                S[0][0] += xa.x * ya.x;  S[0][1] += xa.x * ya.y;
                S[0][2] += xa.x * ya.z;  S[0][3] += xa.x * ya.w;
                S[0][4] += xa.x * yb4.x; S[0][5] += xa.x * yb4.y;
                S[0][6] += xa.x * yb4.z; S[0][7] += xa.x * yb4.w;
                S[1][0] += xa.y * ya.x;  S[1][1] += xa.y * ya.y;
                S[1][2] += xa.y * ya.z;  S[1][3] += xa.y * ya.w;
                S[1][4] += xa.y * yb4.x; S[1][5] += xa.y * yb4.y;
                S[1][6] += xa.y * yb4.z; S[1][7] += xa.y * yb4.w;
            }
        }
        const float gy = gyb + 2.0f * (float)kt;
        #pragma unroll
        for (int r = 0; r < 2; ++r) {
            float tmax = S[r][0];
            #pragma unroll
            for (int j2 = 1; j2 < 8; ++j2) tmax = fmaxf(tmax, S[r][j2]);
            #pragma unroll
            for (int mk = 8; mk >= 1; mk >>= 1) tmax = fmaxf(tmax, __shfl_xor(tmax, mk, 16));
            const float mnew = fmaxf(m_run[r], tmax);
            const float alpha = __expf(m_run[r] - mnew);
            m_run[r] = mnew;
            float psum = 0.f, pu = 0.f;
            #pragma unroll
            for (int j2 = 0; j2 < 8; ++j2) {
                const float p = __expf(S[r][j2] - mnew);
                psum += p; pu += p * gxv[j2];
            }
            den[r] = den[r] * alpha + psum;
            nu[r] = nu[r] * alpha + pu;
            nv[r] = nv[r] * alpha + gy * psum;
        }
    }
    #pragma unroll
    for (int r = 0; r < 2; ++r)
        #pragma unroll
        for (int mk = 8; mk >= 1; mk >>= 1) {
            den[r] += __shfl_xor(den[r], mk, 16);
            nu[r] += __shfl_xor(nu[r], mk, 16);
            nv[r] += __shfl_xor(nv[r], mk, 16);
        }
    if (lane16 == 0) {
        #pragma unroll
        for (int r = 0; r < 2; ++r) {
            const float inv = 1.0f / den[r];
            const int q = q0 + r0 + r;
            *(float2*)(out + ((size_t)b * NPIX + q) * 2) =
                make_float2(nu[r] * inv * 0.03125f - 1.0f, nv[r] * inv * 0.03125f - 1.0f);
        }
    }
}

extern "C" void kernel_launch(void* const* d_in, const int* in_sizes, int n_in,
                              void* d_out, int out_size, void* d_ws, size_t ws_size,
                              hipStream_t stream) {
    const float* x = (const float*)d_in[0];
    const float* y = (const float*)d_in[1];
    float* out = (float*)d_out;
    if (ws_size >= WS_NEED) {
        hipLaunchKernelGGL(conv_y, dim3(512), dim3(256), 0, stream, y, (char*)d_ws);
        hipLaunchKernelGGL(uv_main, dim3(256), dim3(512), 0, stream,
                           (const char*)d_ws, x, out);
    } else {
        hipLaunchKernelGGL(uv_attn_kernel, dim3(512), dim3(256), 0, stream, x, y, out);
    }
}